// Round 5
// baseline (876.832 us; speedup 1.0000x reference)
//
#include <hip/hip_runtime.h>
#include <hip/hip_bf16.h>

#define B_ 128
#define F_ 64
#define R_ 32

typedef __attribute__((ext_vector_type(8))) __bf16 bf16x8;
typedef __attribute__((ext_vector_type(8))) short short8;
typedef __attribute__((ext_vector_type(4))) float f32x4;

__device__ __forceinline__ float sspf(float x) {
    // shifted softplus = max(x,0) + log(1+exp(-|x|)) - ln2, hw exp/log fast paths
    return fmaxf(x, 0.0f) + __logf(1.0f + __expf(-fabsf(x))) - 0.6931471805599453f;
}

__device__ __forceinline__ float bf2f_lo(unsigned int w) { return __uint_as_float(w << 16); }
__device__ __forceinline__ float bf2f_hi(unsigned int w) { return __uint_as_float(w & 0xffff0000u); }
__device__ __forceinline__ float bfbits2f(unsigned int us) { return __uint_as_float(us << 16); }
__device__ __forceinline__ unsigned int f2bf(float f) {
    unsigned int u = __float_as_uint(f);
    return (u + 0x7fffu + ((u >> 16) & 1u)) >> 16;   // RNE
}

// ---- detect pairlist dtype on-device (int64 vs int32). Writes 1 if int64. ----
__global__ void detect_kernel(const void* __restrict__ pl, int* __restrict__ flag, int P) {
    const long long* p64 = (const long long*)pl;
    int ok = 1;
    int n = (P < 64) ? P : 64;
    for (int k = 0; k < n; ++k) {
        long long v = p64[k];
        if (v < 0 || v >= 100000000LL) { ok = 0; break; }
    }
    *flag = ok;
}

__global__ void zero_kernel(float4* __restrict__ p, long long n4) {
    long long i = (long long)blockIdx.x * blockDim.x + threadIdx.x;
    if (i < n4) p[i] = make_float4(0.f, 0.f, 0.f, 0.f);
}

// ---- counting sort by idx_i: histogram ----
__global__ __launch_bounds__(256) void hist_kernel(
    const void* __restrict__ pl, const int* __restrict__ flag,
    int* __restrict__ hist, int P)
{
    int p = blockIdx.x * 256 + threadIdx.x;
    if (p >= P) return;
    int i;
    if (*flag) i = (int)((const long long*)pl)[p];
    else       i = ((const int*)pl)[p];
    atomicAdd(&hist[i], 1);
}

// ---- exclusive prefix scan over NA bins (single block, 1024 threads) ----
__global__ __launch_bounds__(1024) void scan_kernel(
    const int* __restrict__ hist, int* __restrict__ cursor, int NA, int CHUNK)
{
    __shared__ int sums[1024];
    int t = threadIdx.x;
    int b0 = t * CHUNK;
    int b1 = min(b0 + CHUNK, NA);
    int run = 0;
    for (int i = b0; i < b1; ++i) { cursor[i] = run; run += hist[i]; }
    sums[t] = run;
    __syncthreads();
    for (int off = 1; off < 1024; off <<= 1) {
        int v = (t >= off) ? sums[t - off] : 0;
        __syncthreads();
        sums[t] += v;
        __syncthreads();
    }
    int base = (t == 0) ? 0 : sums[t - 1];
    for (int i = b0; i < b1; ++i) cursor[i] += base;
}

// ---- scatter pairs into sorted order, pre-gathering metadata ----
__global__ __launch_bounds__(256) void scatter_kernel(
    const void* __restrict__ pl, const int* __restrict__ flag,
    const float* __restrict__ rcut, int* __restrict__ cursor,
    int4* __restrict__ meta, int P)
{
    int p = blockIdx.x * 256 + threadIdx.x;
    if (p >= P) return;
    int i, j;
    if (*flag) {
        const long long* q = (const long long*)pl;
        i = (int)q[p]; j = (int)q[(size_t)P + p];
    } else {
        const int* q = (const int*)pl;
        i = q[p]; j = q[(size_t)P + p];
    }
    int pos = atomicAdd(&cursor[i], 1);
    meta[pos] = make_int4(i, j, __float_as_int(rcut[p]), p);
}

// ---- prepack weights into per-lane MFMA fragment order (bf16), once ----
__global__ __launch_bounds__(256) void prepack_kernel(
    const float* __restrict__ w1, const float* __restrict__ w2,
    const float* __restrict__ wo1, const float* __restrict__ wo2,
    unsigned short* __restrict__ w1p, unsigned short* __restrict__ w2p,
    unsigned short* __restrict__ wo1p, unsigned short* __restrict__ wo2p)
{
    int t = blockIdx.x * 256 + threadIdx.x;
    if (t < 256) {                       // w1: [32][64] -> 4 ct tiles
        int ct = t >> 6, l = t & 63, g = l >> 4, m = l & 15;
        #pragma unroll
        for (int i = 0; i < 8; ++i)
            w1p[t * 8 + i] = (unsigned short)f2bf(w1[(g * 8 + i) * F_ + ct * 16 + m]);
    } else if (t < 768) {                // w2: [64][64] -> kh(2) x ct(4)
        int q = t - 256;
        int kh = q >> 8, ct = (q >> 6) & 3, l = q & 63, g = l >> 4, m = l & 15;
        #pragma unroll
        for (int i = 0; i < 8; ++i)
            w2p[q * 8 + i] = (unsigned short)f2bf(w2[(kh * 32 + g * 8 + i) * F_ + ct * 16 + m]);
    } else if (t < 2816) {               // w_o2: [128][128] -> ch(2) x kh(4) x ct(4)
        int q = t - 768;
        int l = q & 63, ct = (q >> 6) & 3, kh = (q >> 8) & 3, ch = q >> 10;
        int g = l >> 4, m = l & 15;
        #pragma unroll
        for (int i = 0; i < 8; ++i)
            wo2p[q * 8 + i] = (unsigned short)f2bf(wo2[(kh * 32 + g * 8 + i) * B_ + ch * 64 + ct * 16 + m]);
    } else if (t < 3840) {               // w_o1: [64][128] -> ch(2) x kh(2) x ct(4)
        int q = t - 2816;
        int l = q & 63, ct = (q >> 6) & 3, kh = (q >> 8) & 1, ch = q >> 9;
        int g = l >> 4, m = l & 15;
        #pragma unroll
        for (int i = 0; i < 8; ++i)
            wo1p[q * 8 + i] = (unsigned short)f2bf(wo1[(kh * 32 + g * 8 + i) * B_ + ch * 64 + ct * 16 + m]);
    }
}

// ---- h = x @ w_in + b_in, stored bf16 ----
__global__ __launch_bounds__(256) void h_kernel(
    const float* __restrict__ x, const float* __restrict__ w_in,
    const float* __restrict__ b_in, unsigned short* __restrict__ h, int NA)
{
    int n = blockIdx.x * 256 + threadIdx.x;
    if (n >= NA) return;
    float acc[F_];
    #pragma unroll
    for (int f = 0; f < F_; ++f) acc[f] = b_in[f];
    const float4* xrow = (const float4*)(x + (size_t)n * B_);
    #pragma unroll 2
    for (int rb = 0; rb < B_ / 4; ++rb) {
        float4 xv = xrow[rb];
        const float* w0 = w_in + (size_t)(4 * rb) * F_;
        #pragma unroll
        for (int f = 0; f < F_; ++f) acc[f] = fmaf(xv.x, w0[f], acc[f]);
        #pragma unroll
        for (int f = 0; f < F_; ++f) acc[f] = fmaf(xv.y, w0[F_ + f], acc[f]);
        #pragma unroll
        for (int f = 0; f < F_; ++f) acc[f] = fmaf(xv.z, w0[2 * F_ + f], acc[f]);
        #pragma unroll
        for (int f = 0; f < F_; ++f) acc[f] = fmaf(xv.w, w0[3 * F_ + f], acc[f]);
    }
    uint4* hrow = (uint4*)(h + (size_t)n * F_);
    #pragma unroll
    for (int q = 0; q < F_ / 8; ++q) {
        uint4 ob;
        ob.x = f2bf(acc[8 * q + 0]) | (f2bf(acc[8 * q + 1]) << 16);
        ob.y = f2bf(acc[8 * q + 2]) | (f2bf(acc[8 * q + 3]) << 16);
        ob.z = f2bf(acc[8 * q + 4]) | (f2bf(acc[8 * q + 5]) << 16);
        ob.w = f2bf(acc[8 * q + 6]) | (f2bf(acc[8 * q + 7]) << 16);
        hrow[q] = ob;
    }
}

// ---- MFMA fused pair pipeline (v3): sorted pairs + run-merged atomics ----
__global__ __launch_bounds__(256, 3) void pair_kernel(
    const float* __restrict__ f_ij, const int4* __restrict__ meta,
    const unsigned short* __restrict__ w1p, const float* __restrict__ b1,
    const unsigned short* __restrict__ w2p, const float* __restrict__ b2,
    const unsigned short* __restrict__ h, float* __restrict__ agg,
    int P)
{
    __shared__ __align__(16) unsigned short T[256 * 64];  // [pair][feat] bf16, swizzled
    __shared__ __align__(16) int   ii[256];
    __shared__ __align__(16) int   jj[256];
    __shared__ __align__(16) float rr[256];
    __shared__ __align__(16) int   ss[256];

    const int tid   = threadIdx.x;
    const int lane  = tid & 63;
    const int wv    = tid >> 6;
    const int g     = lane >> 4;
    const int m     = lane & 15;
    const int pbase = blockIdx.x * 256;
    const int wbase = wv * 64;

    // ---- phase 0: sorted-pair metadata -> LDS (own wave's slots only) ----
    {
        int p = pbase + tid;
        int4 mt = (p < P) ? meta[p] : make_int4(0, 0, 0, 0);  // rc bits 0 -> 0.0f
        ii[tid] = mt.x * F_;
        jj[tid] = mt.y * F_;
        rr[tid] = __int_as_float(mt.z);
        ss[tid] = mt.w;
    }

    // ---- prepacked weight fragments: coalesced 16B vector loads ----
    bf16x8 w1f[4], w2f[2][4];
    #pragma unroll
    for (int ct = 0; ct < 4; ++ct)
        w1f[ct] = *(const bf16x8*)&w1p[(ct * 64 + lane) * 8];
    #pragma unroll
    for (int kh = 0; kh < 2; ++kh)
        #pragma unroll
        for (int ct = 0; ct < 4; ++ct)
            w2f[kh][ct] = *(const bf16x8*)&w2p[((kh * 4 + ct) * 64 + lane) * 8];

    float4 b1v[4];
    #pragma unroll
    for (int ft = 0; ft < 4; ++ft) b1v[ft] = *(const float4*)&b1[ft * 16 + g * 4];
    float bias2[4];
    #pragma unroll
    for (int ct = 0; ct < 4; ++ct) bias2[ct] = b2[ct * 16 + m];

    // ---- stage 1 (swapped): C1[ft][pt] = W1^T x f_ij^T, rows via sort indirection ----
    bf16x8 fijf[4];
    #pragma unroll
    for (int pt = 0; pt < 4; ++pt) {
        int src = ss[wbase + pt * 16 + m];
        const float* srcp = f_ij + (size_t)src * R_ + g * 8;
        float4 f0 = *(const float4*)srcp;
        float4 f1 = *(const float4*)(srcp + 4);
        short8 a;
        a[0] = (short)f2bf(f0.x); a[1] = (short)f2bf(f0.y);
        a[2] = (short)f2bf(f0.z); a[3] = (short)f2bf(f0.w);
        a[4] = (short)f2bf(f1.x); a[5] = (short)f2bf(f1.y);
        a[6] = (short)f2bf(f1.z); a[7] = (short)f2bf(f1.w);
        fijf[pt] = __builtin_bit_cast(bf16x8, a);
    }
    f32x4 C1[4][4];
    #pragma unroll
    for (int ft = 0; ft < 4; ++ft)
        #pragma unroll
        for (int pt = 0; pt < 4; ++pt) {
            f32x4 z = {0.f, 0.f, 0.f, 0.f};
            C1[ft][pt] = __builtin_amdgcn_mfma_f32_16x16x32_bf16(w1f[ft], fijf[pt], z, 0, 0, 0);
        }

    // ---- ssp + pack 4 feats -> one 8B swizzled T write per tile ----
    #pragma unroll
    for (int ft = 0; ft < 4; ++ft)
        #pragma unroll
        for (int pt = 0; pt < 4; ++pt) {
            int wp = pt * 16 + m;
            float v0 = sspf(C1[ft][pt][0] + b1v[ft].x);
            float v1 = sspf(C1[ft][pt][1] + b1v[ft].y);
            float v2 = sspf(C1[ft][pt][2] + b1v[ft].z);
            float v3 = sspf(C1[ft][pt][3] + b1v[ft].w);
            uint2 tw;
            tw.x = f2bf(v0) | (f2bf(v1) << 16);
            tw.y = f2bf(v2) | (f2bf(v3) << 16);
            int c = (ft * 4 + g) ^ ((wp & 7) << 1);
            *(uint2*)&T[(wbase + wp) * 64 + c * 4] = tw;
        }

    // ---- stage 2: C2[pair][feat] = T @ W2 ----
    f32x4 C2[4][4];
    #pragma unroll
    for (int rt = 0; rt < 4; ++rt) {
        int wpr = rt * 16 + m;
        int s = wpr & 7;
        const unsigned short* Trow = &T[(wbase + wpr) * 64];
        bf16x8 a0 = *(const bf16x8*)&Trow[((0 + g) ^ s) * 8];
        bf16x8 a1 = *(const bf16x8*)&Trow[((4 + g) ^ s) * 8];
        #pragma unroll
        for (int ct = 0; ct < 4; ++ct) {
            f32x4 c = {0.f, 0.f, 0.f, 0.f};
            c = __builtin_amdgcn_mfma_f32_16x16x32_bf16(a0, w2f[0][ct], c, 0, 0, 0);
            c = __builtin_amdgcn_mfma_f32_16x16x32_bf16(a1, w2f[1][ct], c, 0, 0, 0);
            C2[rt][ct] = c;
        }
    }

    // ---- epilogue: run-merged atomic scatter (sorted: 4-window pairs share i) ----
    #pragma unroll
    for (int rt = 0; rt < 4; ++rt) {
        int base = wbase + rt * 16 + g * 4;
        int4   iv = *(const int4*)&ii[base];
        int4   jv = *(const int4*)&jj[base];
        float4 rv = *(const float4*)&rr[base];
        int   ia[4] = {iv.x, iv.y, iv.z, iv.w};
        int   ja[4] = {jv.x, jv.y, jv.z, jv.w};
        float ra[4] = {rv.x, rv.y, rv.z, rv.w};
        #pragma unroll
        for (int ct = 0; ct < 4; ++ct) {
            int fcol = ct * 16 + m;
            float bv = bias2[ct];
            float vacc = 0.f;
            int icur = ia[0];
            #pragma unroll
            for (int r = 0; r < 4; ++r) {
                float val = (C2[rt][ct][r] + bv) * ra[r] * bfbits2f(h[ja[r] + fcol]);
                if (ia[r] != icur) {
                    atomicAdd(agg + (icur + fcol), vacc);
                    vacc = 0.f;
                    icur = ia[r];
                }
                vacc += val;
            }
            atomicAdd(agg + (icur + fcol), vacc);
        }
    }
}

// ---- u = ssp(agg @ w_o1 + b_o1) via MFMA, stored bf16; grid.y = col half ----
__global__ __launch_bounds__(256) void out1_kernel(
    const float* __restrict__ agg, const unsigned short* __restrict__ wo1p,
    const float* __restrict__ b_o1, unsigned short* __restrict__ u, int NA)
{
    const int tid  = threadIdx.x;
    const int lane = tid & 63;
    const int wv   = tid >> 6;
    const int g    = lane >> 4;
    const int m    = lane & 15;
    const int ch   = blockIdx.y;
    const int rbase = blockIdx.x * 256 + wv * 64;

    bf16x8 wf[2][4];
    #pragma unroll
    for (int kh = 0; kh < 2; ++kh)
        #pragma unroll
        for (int ct = 0; ct < 4; ++ct)
            wf[kh][ct] = *(const bf16x8*)&wo1p[(((ch * 2 + kh) * 4 + ct) * 64 + lane) * 8];
    float bo[4];
    #pragma unroll
    for (int ct = 0; ct < 4; ++ct) bo[ct] = b_o1[ch * 64 + ct * 16 + m];

    f32x4 C[4][4];
    #pragma unroll
    for (int rt = 0; rt < 4; ++rt) {
        int row = rbase + rt * 16 + m;
        if (row >= NA) row = NA - 1;
        const float* ar = agg + (size_t)row * F_;
        bf16x8 af[2];
        #pragma unroll
        for (int kh = 0; kh < 2; ++kh) {
            float4 f0 = *(const float4*)(ar + kh * 32 + g * 8);
            float4 f1 = *(const float4*)(ar + kh * 32 + g * 8 + 4);
            short8 a;
            a[0] = (short)f2bf(f0.x); a[1] = (short)f2bf(f0.y);
            a[2] = (short)f2bf(f0.z); a[3] = (short)f2bf(f0.w);
            a[4] = (short)f2bf(f1.x); a[5] = (short)f2bf(f1.y);
            a[6] = (short)f2bf(f1.z); a[7] = (short)f2bf(f1.w);
            af[kh] = __builtin_bit_cast(bf16x8, a);
        }
        #pragma unroll
        for (int ct = 0; ct < 4; ++ct) {
            f32x4 c = {0.f, 0.f, 0.f, 0.f};
            c = __builtin_amdgcn_mfma_f32_16x16x32_bf16(af[0], wf[0][ct], c, 0, 0, 0);
            c = __builtin_amdgcn_mfma_f32_16x16x32_bf16(af[1], wf[1][ct], c, 0, 0, 0);
            C[rt][ct] = c;
        }
    }
    #pragma unroll
    for (int rt = 0; rt < 4; ++rt)
        #pragma unroll
        for (int ct = 0; ct < 4; ++ct)
            #pragma unroll
            for (int r = 0; r < 4; ++r) {
                int ro = rbase + rt * 16 + g * 4 + r;
                if (ro < NA)
                    u[(size_t)ro * B_ + ch * 64 + ct * 16 + m] =
                        (unsigned short)f2bf(sspf(C[rt][ct][r] + bo[ct]));
            }
}

// ---- out = u @ w_o2 + b_o2 via MFMA; grid.y = col half ----
__global__ __launch_bounds__(256) void out2_kernel(
    const unsigned short* __restrict__ u, const unsigned short* __restrict__ wo2p,
    const float* __restrict__ b_o2, float* __restrict__ out, int NA)
{
    const int tid  = threadIdx.x;
    const int lane = tid & 63;
    const int wv   = tid >> 6;
    const int g    = lane >> 4;
    const int m    = lane & 15;
    const int ch   = blockIdx.y;
    const int rbase = blockIdx.x * 256 + wv * 64;

    bf16x8 wf[4][4];
    #pragma unroll
    for (int kh = 0; kh < 4; ++kh)
        #pragma unroll
        for (int ct = 0; ct < 4; ++ct)
            wf[kh][ct] = *(const bf16x8*)&wo2p[(((ch * 4 + kh) * 4 + ct) * 64 + lane) * 8];
    float bo[4];
    #pragma unroll
    for (int ct = 0; ct < 4; ++ct) bo[ct] = b_o2[ch * 64 + ct * 16 + m];

    f32x4 C[4][4];
    #pragma unroll
    for (int rt = 0; rt < 4; ++rt) {
        int row = rbase + rt * 16 + m;
        if (row >= NA) row = NA - 1;
        const unsigned short* ur = &u[(size_t)row * B_];
        bf16x8 af[4];
        #pragma unroll
        for (int kh = 0; kh < 4; ++kh) af[kh] = *(const bf16x8*)&ur[kh * 32 + g * 8];
        #pragma unroll
        for (int ct = 0; ct < 4; ++ct) {
            f32x4 c = {0.f, 0.f, 0.f, 0.f};
            #pragma unroll
            for (int kh = 0; kh < 4; ++kh)
                c = __builtin_amdgcn_mfma_f32_16x16x32_bf16(af[kh], wf[kh][ct], c, 0, 0, 0);
            C[rt][ct] = c;
        }
    }
    #pragma unroll
    for (int rt = 0; rt < 4; ++rt)
        #pragma unroll
        for (int ct = 0; ct < 4; ++ct)
            #pragma unroll
            for (int r = 0; r < 4; ++r) {
                int ro = rbase + rt * 16 + g * 4 + r;
                if (ro < NA)
                    out[(size_t)ro * B_ + ch * 64 + ct * 16 + m] = C[rt][ct][r] + bo[ct];
            }
}

extern "C" void kernel_launch(void* const* d_in, const int* in_sizes, int n_in,
                              void* d_out, int out_size, void* d_ws, size_t ws_size,
                              hipStream_t stream) {
    const float* x    = (const float*)d_in[0];
    const float* f_ij = (const float*)d_in[1];
    const float* rcut = (const float*)d_in[2];
    const void*  pl   = d_in[3];
    const float* w_in = (const float*)d_in[4];
    const float* b_in = (const float*)d_in[5];
    const float* w_f1 = (const float*)d_in[6];
    const float* b_f1 = (const float*)d_in[7];
    const float* w_f2 = (const float*)d_in[8];
    const float* b_f2 = (const float*)d_in[9];
    const float* w_o1 = (const float*)d_in[10];
    const float* b_o1 = (const float*)d_in[11];
    const float* w_o2 = (const float*)d_in[12];
    const float* b_o2 = (const float*)d_in[13];
    float* out = (float*)d_out;

    int NA = in_sizes[0] / B_;
    int P  = in_sizes[2];

    char* ws = (char*)d_ws;
    size_t off = 0;
    auto alloc = [&](size_t bytes) { size_t o = off; off = (off + bytes + 255) & ~(size_t)255; return o; };
    unsigned short* h_buf = (unsigned short*)(ws + alloc((size_t)NA * F_ * 2));
    float* agg            = (float*)(ws + alloc((size_t)NA * F_ * 4));
    // meta (used only by sort+pair) and u (used only by out1/out2) share storage
    size_t mu_bytes = (size_t)NA * B_ * 2;
    size_t mb = (size_t)P * 16;
    if (mb > mu_bytes) mu_bytes = mb;
    char* mu              = ws + alloc(mu_bytes);
    int4* meta            = (int4*)mu;
    unsigned short* u_buf = (unsigned short*)mu;
    int* hist             = (int*)(ws + alloc((size_t)NA * 4));
    int* cursor           = (int*)(ws + alloc((size_t)NA * 4));
    int* flag             = (int*)(ws + alloc(256));
    unsigned short* w1p   = (unsigned short*)(ws + alloc(2048 * 2));
    unsigned short* w2p   = (unsigned short*)(ws + alloc(4096 * 2));
    unsigned short* wo1p  = (unsigned short*)(ws + alloc(8192 * 2));
    unsigned short* wo2p  = (unsigned short*)(ws + alloc(16384 * 2));

    detect_kernel<<<1, 1, 0, stream>>>(pl, flag, P);
    prepack_kernel<<<15, 256, 0, stream>>>(w_f1, w_f2, w_o1, w_o2, w1p, w2p, wo1p, wo2p);
    h_kernel<<<(NA + 255) / 256, 256, 0, stream>>>(x, w_in, b_in, h_buf, NA);
    long long n4 = (long long)NA * F_ / 4;
    zero_kernel<<<(int)((n4 + 255) / 256), 256, 0, stream>>>((float4*)agg, n4);
    long long h4 = (long long)NA / 4;   // NA ints
    zero_kernel<<<(int)((h4 + 255) / 256), 256, 0, stream>>>((float4*)hist, h4);
    hist_kernel<<<(P + 255) / 256, 256, 0, stream>>>(pl, flag, hist, P);
    int CHUNK = (NA + 1023) / 1024;
    scan_kernel<<<1, 1024, 0, stream>>>(hist, cursor, NA, CHUNK);
    scatter_kernel<<<(P + 255) / 256, 256, 0, stream>>>(pl, flag, rcut, cursor, meta, P);
    pair_kernel<<<(P + 255) / 256, 256, 0, stream>>>(f_ij, meta,
                                                     w1p, b_f1, w2p, b_f2,
                                                     h_buf, agg, P);
    dim3 g3((NA + 255) / 256, 2);
    out1_kernel<<<g3, 256, 0, stream>>>(agg, wo1p, b_o1, u_buf, NA);
    out2_kernel<<<g3, 256, 0, stream>>>(u_buf, wo2p, b_o2, out, NA);
}

// Round 6
// 802.049 us; speedup vs baseline: 1.0932x; 1.0932x over previous
//
#include <hip/hip_runtime.h>
#include <hip/hip_bf16.h>

#define B_ 128
#define F_ 64
#define R_ 32
#define FPB 524288            // fixed-point positivity bias = 2^19
#define FPS 4096.0f           // fixed-point scale = 2^12
#define FPSI 2.44140625e-4f   // 2^-12

typedef __attribute__((ext_vector_type(8))) __bf16 bf16x8;
typedef __attribute__((ext_vector_type(8))) short short8;
typedef __attribute__((ext_vector_type(4))) float f32x4;

__device__ __forceinline__ float sspf(float x) {
    // shifted softplus = max(x,0) + log(1+exp(-|x|)) - ln2, hw exp/log fast paths
    return fmaxf(x, 0.0f) + __logf(1.0f + __expf(-fabsf(x))) - 0.6931471805599453f;
}

__device__ __forceinline__ float bf2f_lo(unsigned int w) { return __uint_as_float(w << 16); }
__device__ __forceinline__ float bf2f_hi(unsigned int w) { return __uint_as_float(w & 0xffff0000u); }
__device__ __forceinline__ float bfbits2f(unsigned int us) { return __uint_as_float(us << 16); }
__device__ __forceinline__ unsigned int f2bf(float f) {
    unsigned int u = __float_as_uint(f);
    return (u + 0x7fffu + ((u >> 16) & 1u)) >> 16;   // RNE
}

// ---- detect pairlist dtype (int64 vs int32), 64-lane parallel ----
__global__ void detect_kernel(const void* __restrict__ pl, int* __restrict__ flag, int P) {
    int n = (P < 64) ? P : 64;
    const long long* p64 = (const long long*)pl;
    bool bad = false;
    if ((int)threadIdx.x < n) {
        long long v = p64[threadIdx.x];
        bad = (v < 0) || (v >= 100000000LL);
    }
    unsigned long long b = __ballot(bad);
    if (threadIdx.x == 0) *flag = (b == 0ULL) ? 1 : 0;
}

__global__ void zero_kernel(float4* __restrict__ p, long long n4) {
    long long i = (long long)blockIdx.x * blockDim.x + threadIdx.x;
    if (i < n4) p[i] = make_float4(0.f, 0.f, 0.f, 0.f);
}

// ---- prepack weights into per-lane MFMA fragment order (bf16), once ----
// frag element i of lane l (g=l>>4, m=l&15), tile ct: W[k=kh*32+g*8+i][n=ct*16+m]
__global__ __launch_bounds__(256) void prepack_kernel(
    const float* __restrict__ w1, const float* __restrict__ w2,
    const float* __restrict__ wo1, const float* __restrict__ wo2,
    unsigned short* __restrict__ w1p, unsigned short* __restrict__ w2p,
    unsigned short* __restrict__ wo1p, unsigned short* __restrict__ wo2p)
{
    int t = blockIdx.x * 256 + threadIdx.x;
    if (t < 256) {                       // w1: [32][64] -> 4 ct tiles
        int ct = t >> 6, l = t & 63, g = l >> 4, m = l & 15;
        #pragma unroll
        for (int i = 0; i < 8; ++i)
            w1p[t * 8 + i] = (unsigned short)f2bf(w1[(g * 8 + i) * F_ + ct * 16 + m]);
    } else if (t < 768) {                // w2: [64][64] -> kh(2) x ct(4)
        int q = t - 256;
        int kh = q >> 8, ct = (q >> 6) & 3, l = q & 63, g = l >> 4, m = l & 15;
        #pragma unroll
        for (int i = 0; i < 8; ++i)
            w2p[q * 8 + i] = (unsigned short)f2bf(w2[(kh * 32 + g * 8 + i) * F_ + ct * 16 + m]);
    } else if (t < 2816) {               // w_o2: [128][128] -> ch(2) x kh(4) x ct(4)
        int q = t - 768;
        int l = q & 63, ct = (q >> 6) & 3, kh = (q >> 8) & 3, ch = q >> 10;
        int g = l >> 4, m = l & 15;
        #pragma unroll
        for (int i = 0; i < 8; ++i)
            wo2p[q * 8 + i] = (unsigned short)f2bf(wo2[(kh * 32 + g * 8 + i) * B_ + ch * 64 + ct * 16 + m]);
    } else if (t < 3840) {               // w_o1: [64][128] -> ch(2) x kh(2) x ct(4)
        int q = t - 2816;
        int l = q & 63, ct = (q >> 6) & 3, kh = (q >> 8) & 1, ch = q >> 9;
        int g = l >> 4, m = l & 15;
        #pragma unroll
        for (int i = 0; i < 8; ++i)
            wo1p[q * 8 + i] = (unsigned short)f2bf(wo1[(kh * 32 + g * 8 + i) * B_ + ch * 64 + ct * 16 + m]);
    }
}

// ---- h = x @ w_in + b_in, stored bf16 ----
__global__ __launch_bounds__(256) void h_kernel(
    const float* __restrict__ x, const float* __restrict__ w_in,
    const float* __restrict__ b_in, unsigned short* __restrict__ h, int NA)
{
    int n = blockIdx.x * 256 + threadIdx.x;
    if (n >= NA) return;
    float acc[F_];
    #pragma unroll
    for (int f = 0; f < F_; ++f) acc[f] = b_in[f];
    const float4* xrow = (const float4*)(x + (size_t)n * B_);
    #pragma unroll 2
    for (int rb = 0; rb < B_ / 4; ++rb) {
        float4 xv = xrow[rb];
        const float* w0 = w_in + (size_t)(4 * rb) * F_;
        #pragma unroll
        for (int f = 0; f < F_; ++f) acc[f] = fmaf(xv.x, w0[f], acc[f]);
        #pragma unroll
        for (int f = 0; f < F_; ++f) acc[f] = fmaf(xv.y, w0[F_ + f], acc[f]);
        #pragma unroll
        for (int f = 0; f < F_; ++f) acc[f] = fmaf(xv.z, w0[2 * F_ + f], acc[f]);
        #pragma unroll
        for (int f = 0; f < F_; ++f) acc[f] = fmaf(xv.w, w0[3 * F_ + f], acc[f]);
    }
    uint4* hrow = (uint4*)(h + (size_t)n * F_);
    #pragma unroll
    for (int q = 0; q < F_ / 8; ++q) {
        uint4 ob;
        ob.x = f2bf(acc[8 * q + 0]) | (f2bf(acc[8 * q + 1]) << 16);
        ob.y = f2bf(acc[8 * q + 2]) | (f2bf(acc[8 * q + 3]) << 16);
        ob.z = f2bf(acc[8 * q + 4]) | (f2bf(acc[8 * q + 5]) << 16);
        ob.w = f2bf(acc[8 * q + 6]) | (f2bf(acc[8 * q + 7]) << 16);
        hrow[q] = ob;
    }
}

// ---- MFMA fused pair pipeline (v4): unsorted + packed u64 fixed-point atomics ----
// Stage1 swapped (C1[feat][pair]) as in v2. Stage2 ALSO swapped: C2[feat][pair] =
// mfma(W2-frag-as-A, T-frag-as-B), so each lane holds 4 CONSECUTIVE features of
// one pair -> two u64 atomicAdds update 4 int32 fixed-point accumulators.
// Fixed-point: e = rn(x*2^12) + 2^19 (positive), per-bin sums < 2^26 -> no carry
// between packed lanes; exact integer associativity -> deterministic agg.
__global__ __launch_bounds__(256, 4) void pair_kernel(
    const float* __restrict__ f_ij, const float* __restrict__ rcut,
    const void* __restrict__ pl, const int* __restrict__ flag,
    const unsigned short* __restrict__ w1p, const float* __restrict__ b1,
    const unsigned short* __restrict__ w2p, const float* __restrict__ b2,
    const unsigned short* __restrict__ h, int* __restrict__ agg_fix,
    int* __restrict__ cnt, int P)
{
    __shared__ __align__(16) unsigned short T[256 * 64];  // [pair][feat] bf16, swizzled
    __shared__ __align__(16) int   ii[256];
    __shared__ __align__(16) int   jj[256];
    __shared__ __align__(16) float rr[256];

    const int tid   = threadIdx.x;
    const int lane  = tid & 63;
    const int wv    = tid >> 6;
    const int g     = lane >> 4;
    const int m     = lane & 15;
    const int pbase = blockIdx.x * 256;
    const int wbase = wv * 64;

    // ---- phase 0: pair metadata -> LDS (own wave's slots only) ----
    {
        int p = pbase + tid;
        bool valid = (p < P);
        int pc = valid ? p : (P > 0 ? P - 1 : 0);
        long long i_, j_;
        if (*flag) {
            const long long* p64 = (const long long*)pl;
            i_ = p64[pc]; j_ = p64[(size_t)P + pc];
        } else {
            const int* p32 = (const int*)pl;
            i_ = p32[pc]; j_ = p32[(size_t)P + pc];
        }
        ii[tid] = valid ? (int)i_ : 0;    // invalid -> atom 0 with rc=0; bias is
        jj[tid] = valid ? (int)j_ : 0;    // counted in cnt[0] too -> decodes to +0
        rr[tid] = valid ? rcut[pc] : 0.0f;
    }

    // ---- prepacked weight fragments: coalesced 16B vector loads ----
    bf16x8 w1f[4], w2f[2][4];
    #pragma unroll
    for (int ct = 0; ct < 4; ++ct)
        w1f[ct] = *(const bf16x8*)&w1p[(ct * 64 + lane) * 8];
    #pragma unroll
    for (int kh = 0; kh < 2; ++kh)
        #pragma unroll
        for (int ct = 0; ct < 4; ++ct)
            w2f[kh][ct] = *(const bf16x8*)&w2p[((kh * 4 + ct) * 64 + lane) * 8];

    float4 b1v[4], b2v[4];
    #pragma unroll
    for (int ft = 0; ft < 4; ++ft) {
        b1v[ft] = *(const float4*)&b1[ft * 16 + g * 4];
        b2v[ft] = *(const float4*)&b2[ft * 16 + g * 4];
    }

    // ---- stage 1 (swapped): C1[ft][pt] = W1^T x f_ij^T ----
    bf16x8 fijf[4];
    #pragma unroll
    for (int pt = 0; pt < 4; ++pt) {
        int row = pbase + wbase + pt * 16 + m;
        if (row >= P) row = (P > 0 ? P - 1 : 0);
        const float* srcp = f_ij + (size_t)row * R_ + g * 8;
        float4 f0 = *(const float4*)srcp;
        float4 f1 = *(const float4*)(srcp + 4);
        short8 a;
        a[0] = (short)f2bf(f0.x); a[1] = (short)f2bf(f0.y);
        a[2] = (short)f2bf(f0.z); a[3] = (short)f2bf(f0.w);
        a[4] = (short)f2bf(f1.x); a[5] = (short)f2bf(f1.y);
        a[6] = (short)f2bf(f1.z); a[7] = (short)f2bf(f1.w);
        fijf[pt] = __builtin_bit_cast(bf16x8, a);
    }
    f32x4 C1[4][4];
    #pragma unroll
    for (int ft = 0; ft < 4; ++ft)
        #pragma unroll
        for (int pt = 0; pt < 4; ++pt) {
            f32x4 z = {0.f, 0.f, 0.f, 0.f};
            C1[ft][pt] = __builtin_amdgcn_mfma_f32_16x16x32_bf16(w1f[ft], fijf[pt], z, 0, 0, 0);
        }

    // ---- ssp + pack 4 feats -> one 8B swizzled T write per tile ----
    #pragma unroll
    for (int ft = 0; ft < 4; ++ft)
        #pragma unroll
        for (int pt = 0; pt < 4; ++pt) {
            int wp = pt * 16 + m;
            float v0 = sspf(C1[ft][pt][0] + b1v[ft].x);
            float v1 = sspf(C1[ft][pt][1] + b1v[ft].y);
            float v2 = sspf(C1[ft][pt][2] + b1v[ft].z);
            float v3 = sspf(C1[ft][pt][3] + b1v[ft].w);
            uint2 tw;
            tw.x = f2bf(v0) | (f2bf(v1) << 16);
            tw.y = f2bf(v2) | (f2bf(v3) << 16);
            int c = (ft * 4 + g) ^ ((wp & 7) << 1);
            *(uint2*)&T[(wbase + wp) * 64 + c * 4] = tw;
        }

    // ---- stage 2 (swapped): C2[ft][pt] with rows=features, cols=pairs ----
    f32x4 C2[4][4];
    #pragma unroll
    for (int pt = 0; pt < 4; ++pt) {
        int wpr = pt * 16 + m;
        int s = wpr & 7;
        const unsigned short* Trow = &T[(wbase + wpr) * 64];
        bf16x8 t0 = *(const bf16x8*)&Trow[((0 + g) ^ s) * 8];
        bf16x8 t1 = *(const bf16x8*)&Trow[((4 + g) ^ s) * 8];
        #pragma unroll
        for (int ft = 0; ft < 4; ++ft) {
            f32x4 c = {0.f, 0.f, 0.f, 0.f};
            c = __builtin_amdgcn_mfma_f32_16x16x32_bf16(w2f[0][ft], t0, c, 0, 0, 0);
            c = __builtin_amdgcn_mfma_f32_16x16x32_bf16(w2f[1][ft], t1, c, 0, 0, 0);
            C2[ft][pt] = c;
        }
    }

    // ---- epilogue: packed u64 fixed-point atomic scatter ----
    #pragma unroll
    for (int pt = 0; pt < 4; ++pt) {
        int pp = wbase + pt * 16 + m;
        int i_ = ii[pp];
        int j_ = jj[pp];
        float rc = rr[pp];
        if (g == 0) atomicAdd(&cnt[i_], 1);       // one count per pair
        int* aggrow = agg_fix + i_ * F_;
        const unsigned short* hrow = h + j_ * F_;
        #pragma unroll
        for (int ft = 0; ft < 4; ++ft) {
            int f0 = ft * 16 + g * 4;
            ushort4 hv = *(const ushort4*)&hrow[f0];
            float x0 = (C2[ft][pt][0] + b2v[ft].x) * rc * bfbits2f(hv.x);
            float x1 = (C2[ft][pt][1] + b2v[ft].y) * rc * bfbits2f(hv.y);
            float x2 = (C2[ft][pt][2] + b2v[ft].z) * rc * bfbits2f(hv.z);
            float x3 = (C2[ft][pt][3] + b2v[ft].w) * rc * bfbits2f(hv.w);
            unsigned int e0 = (unsigned int)(__float2int_rn(x0 * FPS) + FPB);
            unsigned int e1 = (unsigned int)(__float2int_rn(x1 * FPS) + FPB);
            unsigned int e2 = (unsigned int)(__float2int_rn(x2 * FPS) + FPB);
            unsigned int e3 = (unsigned int)(__float2int_rn(x3 * FPS) + FPB);
            atomicAdd((unsigned long long*)(aggrow + f0),
                      (unsigned long long)e0 | ((unsigned long long)e1 << 32));
            atomicAdd((unsigned long long*)(aggrow + f0 + 2),
                      (unsigned long long)e2 | ((unsigned long long)e3 << 32));
        }
    }
}

// ---- u = ssp(decode(agg_fix) @ w_o1 + b_o1) via MFMA, bf16; grid.y = col half ----
__global__ __launch_bounds__(256) void out1_kernel(
    const int* __restrict__ agg_fix, const int* __restrict__ cnt,
    const unsigned short* __restrict__ wo1p,
    const float* __restrict__ b_o1, unsigned short* __restrict__ u, int NA)
{
    const int tid  = threadIdx.x;
    const int lane = tid & 63;
    const int wv   = tid >> 6;
    const int g    = lane >> 4;
    const int m    = lane & 15;
    const int ch   = blockIdx.y;
    const int rbase = blockIdx.x * 256 + wv * 64;

    bf16x8 wf[2][4];
    #pragma unroll
    for (int kh = 0; kh < 2; ++kh)
        #pragma unroll
        for (int ct = 0; ct < 4; ++ct)
            wf[kh][ct] = *(const bf16x8*)&wo1p[(((ch * 2 + kh) * 4 + ct) * 64 + lane) * 8];
    float bo[4];
    #pragma unroll
    for (int ct = 0; ct < 4; ++ct) bo[ct] = b_o1[ch * 64 + ct * 16 + m];

    f32x4 C[4][4];
    #pragma unroll
    for (int rt = 0; rt < 4; ++rt) {
        int row = rbase + rt * 16 + m;
        if (row >= NA) row = NA - 1;
        const int* ar = agg_fix + (size_t)row * F_;
        int Kb = cnt[row] * FPB;               // exact: K<=~60, K*2^19 < 2^26
        bf16x8 af[2];
        #pragma unroll
        for (int kh = 0; kh < 2; ++kh) {
            int4 v0 = *(const int4*)(ar + kh * 32 + g * 8);
            int4 v1 = *(const int4*)(ar + kh * 32 + g * 8 + 4);
            short8 a;
            a[0] = (short)f2bf((float)(v0.x - Kb) * FPSI);
            a[1] = (short)f2bf((float)(v0.y - Kb) * FPSI);
            a[2] = (short)f2bf((float)(v0.z - Kb) * FPSI);
            a[3] = (short)f2bf((float)(v0.w - Kb) * FPSI);
            a[4] = (short)f2bf((float)(v1.x - Kb) * FPSI);
            a[5] = (short)f2bf((float)(v1.y - Kb) * FPSI);
            a[6] = (short)f2bf((float)(v1.z - Kb) * FPSI);
            a[7] = (short)f2bf((float)(v1.w - Kb) * FPSI);
            af[kh] = __builtin_bit_cast(bf16x8, a);
        }
        #pragma unroll
        for (int ct = 0; ct < 4; ++ct) {
            f32x4 c = {0.f, 0.f, 0.f, 0.f};
            c = __builtin_amdgcn_mfma_f32_16x16x32_bf16(af[0], wf[0][ct], c, 0, 0, 0);
            c = __builtin_amdgcn_mfma_f32_16x16x32_bf16(af[1], wf[1][ct], c, 0, 0, 0);
            C[rt][ct] = c;
        }
    }
    #pragma unroll
    for (int rt = 0; rt < 4; ++rt)
        #pragma unroll
        for (int ct = 0; ct < 4; ++ct)
            #pragma unroll
            for (int r = 0; r < 4; ++r) {
                int ro = rbase + rt * 16 + g * 4 + r;
                if (ro < NA)
                    u[(size_t)ro * B_ + ch * 64 + ct * 16 + m] =
                        (unsigned short)f2bf(sspf(C[rt][ct][r] + bo[ct]));
            }
}

// ---- out = u @ w_o2 + b_o2 via MFMA; grid.y = col half ----
__global__ __launch_bounds__(256) void out2_kernel(
    const unsigned short* __restrict__ u, const unsigned short* __restrict__ wo2p,
    const float* __restrict__ b_o2, float* __restrict__ out, int NA)
{
    const int tid  = threadIdx.x;
    const int lane = tid & 63;
    const int wv   = tid >> 6;
    const int g    = lane >> 4;
    const int m    = lane & 15;
    const int ch   = blockIdx.y;
    const int rbase = blockIdx.x * 256 + wv * 64;

    bf16x8 wf[4][4];
    #pragma unroll
    for (int kh = 0; kh < 4; ++kh)
        #pragma unroll
        for (int ct = 0; ct < 4; ++ct)
            wf[kh][ct] = *(const bf16x8*)&wo2p[(((ch * 4 + kh) * 4 + ct) * 64 + lane) * 8];
    float bo[4];
    #pragma unroll
    for (int ct = 0; ct < 4; ++ct) bo[ct] = b_o2[ch * 64 + ct * 16 + m];

    f32x4 C[4][4];
    #pragma unroll
    for (int rt = 0; rt < 4; ++rt) {
        int row = rbase + rt * 16 + m;
        if (row >= NA) row = NA - 1;
        const unsigned short* ur = &u[(size_t)row * B_];
        bf16x8 af[4];
        #pragma unroll
        for (int kh = 0; kh < 4; ++kh) af[kh] = *(const bf16x8*)&ur[kh * 32 + g * 8];
        #pragma unroll
        for (int ct = 0; ct < 4; ++ct) {
            f32x4 c = {0.f, 0.f, 0.f, 0.f};
            #pragma unroll
            for (int kh = 0; kh < 4; ++kh)
                c = __builtin_amdgcn_mfma_f32_16x16x32_bf16(af[kh], wf[kh][ct], c, 0, 0, 0);
            C[rt][ct] = c;
        }
    }
    #pragma unroll
    for (int rt = 0; rt < 4; ++rt)
        #pragma unroll
        for (int ct = 0; ct < 4; ++ct)
            #pragma unroll
            for (int r = 0; r < 4; ++r) {
                int ro = rbase + rt * 16 + g * 4 + r;
                if (ro < NA)
                    out[(size_t)ro * B_ + ch * 64 + ct * 16 + m] = C[rt][ct][r] + bo[ct];
            }
}

extern "C" void kernel_launch(void* const* d_in, const int* in_sizes, int n_in,
                              void* d_out, int out_size, void* d_ws, size_t ws_size,
                              hipStream_t stream) {
    const float* x    = (const float*)d_in[0];
    const float* f_ij = (const float*)d_in[1];
    const float* rcut = (const float*)d_in[2];
    const void*  pl   = d_in[3];
    const float* w_in = (const float*)d_in[4];
    const float* b_in = (const float*)d_in[5];
    const float* w_f1 = (const float*)d_in[6];
    const float* b_f1 = (const float*)d_in[7];
    const float* w_f2 = (const float*)d_in[8];
    const float* b_f2 = (const float*)d_in[9];
    const float* w_o1 = (const float*)d_in[10];
    const float* b_o1 = (const float*)d_in[11];
    const float* w_o2 = (const float*)d_in[12];
    const float* b_o2 = (const float*)d_in[13];
    float* out = (float*)d_out;

    int NA = in_sizes[0] / B_;
    int P  = in_sizes[2];

    char* ws = (char*)d_ws;
    size_t off = 0;
    auto alloc = [&](size_t bytes) { size_t o = off; off = (off + bytes + 255) & ~(size_t)255; return o; };
    unsigned short* h_buf = (unsigned short*)(ws + alloc((size_t)NA * F_ * 2));
    // agg_fix (int32[NA][64]) and cnt (int32[NA]) contiguous -> one zero pass
    int* agg_fix          = (int*)(ws + alloc((size_t)NA * (F_ + 1) * 4 + 16));
    int* cnt              = agg_fix + (size_t)NA * F_;
    unsigned short* u_buf = (unsigned short*)(ws + alloc((size_t)NA * B_ * 2));
    int* flag             = (int*)(ws + alloc(256));
    unsigned short* w1p   = (unsigned short*)(ws + alloc(2048 * 2));
    unsigned short* w2p   = (unsigned short*)(ws + alloc(4096 * 2));
    unsigned short* wo1p  = (unsigned short*)(ws + alloc(8192 * 2));
    unsigned short* wo2p  = (unsigned short*)(ws + alloc(16384 * 2));

    detect_kernel<<<1, 64, 0, stream>>>(pl, flag, P);
    prepack_kernel<<<15, 256, 0, stream>>>(w_f1, w_f2, w_o1, w_o2, w1p, w2p, wo1p, wo2p);
    h_kernel<<<(NA + 255) / 256, 256, 0, stream>>>(x, w_in, b_in, h_buf, NA);
    long long nz4 = ((long long)NA * (F_ + 1) + 3) / 4;
    zero_kernel<<<(int)((nz4 + 255) / 256), 256, 0, stream>>>((float4*)agg_fix, nz4);
    pair_kernel<<<(P + 255) / 256, 256, 0, stream>>>(f_ij, rcut, pl, flag,
                                                     w1p, b_f1, w2p, b_f2,
                                                     h_buf, agg_fix, cnt, P);
    dim3 g3((NA + 255) / 256, 2);
    out1_kernel<<<g3, 256, 0, stream>>>(agg_fix, cnt, wo1p, b_o1, u_buf, NA);
    out2_kernel<<<g3, 256, 0, stream>>>(u_buf, wo2p, b_o2, out, NA);
}